// Round 12
// baseline (426.845 us; speedup 1.0000x reference)
//
#include <hip/hip_runtime.h>

#define KDIM 8192
#define NDIM 16384
#define BDIM 16
#define NBLK 8                        // KDIM/1024 scale blocks per row
#define TN 8                          // output rows per wave
#define WAVES 4
#define ROWS_PER_BLOCK (WAVES * TN)   // 32
#define KC 128                        // k per chunk (64 lanes * 2)
#define NCHUNK (KDIM / KC)            // 64

// Barrier-free streaming dequant-GEMM. No LDS, no __syncthreads: each wave is
// autonomous. W and x are explicitly double-buffered in registers (dwordx2
// loads), so the compiler emits counted vmcnt(N) waits and every wave keeps
// ~24 loads (~12KB) in flight across its whole compute phase; 8 drifting
// waves/CU keep the HBM queue full (rounds 7/10: barriers forced vmcnt(0)
// each phase -> 50% HBM duty).
// launch_bounds(256) with NO min-waves arg (measured table: (256,4)->64 VGPR,
// (256,2)->128, omitted->64 -- all spill; (256)->live-set-driven ~250, none).
__global__ __launch_bounds__(256) void int8lin_kernel(
    const float* __restrict__ x,
    const int* __restrict__ qw,
    const float* __restrict__ scales,
    const float* __restrict__ bias,
    float* __restrict__ out)
{
    const int lane = threadIdx.x & 63;
    const int wave = threadIdx.x >> 6;
    const int n0 = blockIdx.x * ROWS_PER_BLOCK + wave * TN;
    const int kbase = lane * 2;

    float acc[BDIM][TN];
#pragma unroll
    for (int i = 0; i < BDIM; ++i)
#pragma unroll
        for (int j = 0; j < TN; ++j) acc[i][j] = 0.f;

    const int* wp = qw + (size_t)n0 * KDIM + kbase;
    const float* xp = x + kbase;

    auto LOADW = [&](int2* w, int c) {
#pragma unroll
        for (int j = 0; j < TN; ++j)
            w[j] = *reinterpret_cast<const int2*>(wp + (size_t)j * KDIM + c * KC);
    };
    auto LOADX = [&](float2* xv, int c) {
#pragma unroll
        for (int i = 0; i < BDIM; ++i)
            xv[i] = *reinterpret_cast<const float2*>(xp + (size_t)i * KDIM + c * KC);
    };
    auto COMPUTE = [&](const int2* w, const float2* xv, int c) {
        float s[TN], wf[TN][2];
#pragma unroll
        for (int j = 0; j < TN; ++j)
            s[j] = scales[(size_t)(n0 + j) * NBLK + (c >> 3)];
#pragma unroll
        for (int j = 0; j < TN; ++j) {
            wf[j][0] = (float)w[j].x * s[j];
            wf[j][1] = (float)w[j].y * s[j];
        }
#pragma unroll
        for (int i = 0; i < BDIM; ++i)
#pragma unroll
            for (int j = 0; j < TN; ++j) {
                acc[i][j] = fmaf(xv[i].x, wf[j][0], acc[i][j]);
                acc[i][j] = fmaf(xv[i].y, wf[j][1], acc[i][j]);
            }
    };

    int2   wA[TN], wB[TN];
    float2 xA[BDIM], xB[BDIM];

    LOADW(wA, 0);
    LOADX(xA, 0);

#pragma unroll 1
    for (int c = 0; c < NCHUNK; c += 2) {
        LOADW(wB, c + 1);                 // next chunk in flight under compute
        LOADX(xB, c + 1);
        COMPUTE(wA, xA, c);

        const int cn = (c + 2 < NCHUNK) ? c + 2 : NCHUNK - 1;  // tail: harmless reload
        LOADW(wA, cn);
        LOADX(xA, cn);
        COMPUTE(wB, xB, c + 1);
    }

    // 64-lane butterfly reduction; lane 0 stores the wave's 16xTN tile.
#pragma unroll
    for (int i = 0; i < BDIM; ++i)
#pragma unroll
        for (int j = 0; j < TN; ++j) {
            float v = acc[i][j];
#pragma unroll
            for (int off = 32; off >= 1; off >>= 1) v += __shfl_xor(v, off, 64);
            acc[i][j] = v;
        }

    if (lane == 0) {
#pragma unroll
        for (int j = 0; j < TN; ++j) {
            const float b = bias[n0 + j];
#pragma unroll
            for (int i = 0; i < BDIM; ++i)
                out[(size_t)i * NDIM + (n0 + j)] = acc[i][j] + b;
        }
    }
}

extern "C" void kernel_launch(void* const* d_in, const int* in_sizes, int n_in,
                              void* d_out, int out_size, void* d_ws, size_t ws_size,
                              hipStream_t stream) {
    const float* x      = (const float*)d_in[0];
    const int*   qw     = (const int*)d_in[1];
    const float* scales = (const float*)d_in[2];
    const float* bias   = (const float*)d_in[3];
    float*       out    = (float*)d_out;

    dim3 grid(NDIM / ROWS_PER_BLOCK);   // 512 blocks = 2 per CU
    dim3 block(256);                     // 4 independent waves
    int8lin_kernel<<<grid, block, 0, stream>>>(x, qw, scales, bias, out);
}

// Round 13
// 143.628 us; speedup vs baseline: 2.9719x; 2.9719x over previous
//
#include <hip/hip_runtime.h>

#define KDIM 8192
#define NDIM 16384
#define BDIM 16
#define NBLK 8                        // KDIM/1024 scale blocks per row
#define TN 8                          // output rows per wave
#define WAVES 4
#define ROWS_PER_BLOCK (WAVES * TN)   // 32
#define KC 256                        // k per chunk (64 lanes * 4)
#define NCHUNK (KDIM / KC)            // 32

// global->LDS direct copy, 16B/lane: LDS dest wave-uniform, global src per-lane.
__device__ __forceinline__ void gload_lds16(const float* g, float* l) {
    __builtin_amdgcn_global_load_lds(
        (const __attribute__((address_space(1))) unsigned int*)(uintptr_t)g,
        (__attribute__((address_space(3))) unsigned int*)(uintptr_t)l,
        16, 0, 0);
}

// R10 structure (x LDS-dbuf + W reg-dbuf, 153us) with ONE change: the
// __syncthreads (which drains vmcnt(0), killing the W prefetch every chunk ->
// ~55% HBM duty) is replaced by counted "s_waitcnt vmcnt(8)" + raw s_barrier.
// Per chunk each wave issues exactly 4 gload_lds (x, oldest) then 8 W loads;
// vmcnt(8) retires only the x-stage, the 8 W loads cross the barrier with a
// full phase (~1100cy) of flight time. sched_barrier(0) pins the load block
// (round 12: unpinned prefetch gets sunk to uses -> serial chain).
// Scales go via SMEM (readfirstlane-uniform) so vmem count stays exact.
// launch_bounds(256), NO min-waves arg (measured: (256,4)/(256,2)/omitted ->
// 64/128/64 VGPR, all spill; (256) -> live-set-driven, no spill).
__global__ __launch_bounds__(256) void int8lin_kernel(
    const float* __restrict__ x,
    const int* __restrict__ qw,
    const float* __restrict__ scales,
    const float* __restrict__ bias,
    float* __restrict__ out)
{
    __shared__ float xbuf[2][BDIM][KC];   // 2 x 16 KB

    const int tid  = threadIdx.x;
    const int lane = tid & 63;
    const int wave = __builtin_amdgcn_readfirstlane(tid) >> 6;   // SGPR-uniform
    const int n0 = blockIdx.x * ROWS_PER_BLOCK + wave * TN;
    const int kbase = lane * 4;

    float acc[BDIM][TN];
#pragma unroll
    for (int i = 0; i < BDIM; ++i)
#pragma unroll
        for (int j = 0; j < TN; ++j) acc[i][j] = 0.f;

    // x-stage: wave stages batch rows 4w..4w+3 of chunk c into xbuf[pb].
    auto STAGE = [&](int c, int pb) {
#pragma unroll
        for (int q = 0; q < 4; ++q) {
            const int r = wave * 4 + q;
            gload_lds16(x + (size_t)r * KDIM + c * KC + kbase, &xbuf[pb][r][0]);
        }
    };

    auto LOADW = [&](int4* w, int c) {
#pragma unroll
        for (int j = 0; j < TN; ++j)
            w[j] = *reinterpret_cast<const int4*>(qw + (size_t)(n0 + j) * KDIM + c * KC + kbase);
    };

    auto COMPUTE = [&](const int4* w, const float* sc, int pb) {
        float wf[TN][4];
#pragma unroll
        for (int j = 0; j < TN; ++j) {
            wf[j][0] = (float)w[j].x * sc[j];
            wf[j][1] = (float)w[j].y * sc[j];
            wf[j][2] = (float)w[j].z * sc[j];
            wf[j][3] = (float)w[j].w * sc[j];
        }
#pragma unroll
        for (int i = 0; i < BDIM; ++i) {
            const float4 xv = *reinterpret_cast<const float4*>(&xbuf[pb][i][kbase]);
#pragma unroll
            for (int j = 0; j < TN; ++j) {
                acc[i][j] = fmaf(xv.x, wf[j][0], acc[i][j]);
                acc[i][j] = fmaf(xv.y, wf[j][1], acc[i][j]);
                acc[i][j] = fmaf(xv.z, wf[j][2], acc[i][j]);
                acc[i][j] = fmaf(xv.w, wf[j][3], acc[i][j]);
            }
        }
    };

    // Counted barrier: retire only the 4 oldest (x-stage) vmem ops; the 8 W
    // loads issued after them stay in flight across the barrier.
#define WAIT_BAR()                                            \
    do {                                                      \
        asm volatile("s_waitcnt vmcnt(8)" ::: "memory");      \
        __builtin_amdgcn_s_barrier();                         \
        __builtin_amdgcn_sched_barrier(0);                    \
    } while (0)

    int4 wA[TN], wB[TN];
    STAGE(0, 0);       // 4 vmem (oldest)
    LOADW(wA, 0);      // 8 vmem
    __builtin_amdgcn_sched_barrier(0);

#pragma unroll 1
    for (int blk = 0; blk < NBLK; ++blk) {
        // Per-row scales for this 1024-k block: uniform address -> SMEM (lgkm).
        float sc[TN];
#pragma unroll
        for (int j = 0; j < TN; ++j)
            sc[j] = scales[(size_t)(n0 + j) * NBLK + blk];

#pragma unroll 1
        for (int cc = 0; cc < 4; cc += 2) {
            const int c = blk * 4 + cc;

            WAIT_BAR();                  // xbuf[0] (chunk c) ready; wA in flight/near
            STAGE(c + 1, 1);             // 4 vmem
            LOADW(wB, c + 1);            // 8 vmem
            __builtin_amdgcn_sched_barrier(0);   // pin prefetch above compute
            COMPUTE(wA, sc, 0);          // auto counted vmcnt for wA

            WAIT_BAR();                  // xbuf[1] (chunk c+1) ready
            if (c + 2 < NCHUNK) {
                STAGE(c + 2, 0);
                LOADW(wA, c + 2);
            }
            __builtin_amdgcn_sched_barrier(0);
            COMPUTE(wB, sc, 1);
        }
    }
#undef WAIT_BAR

    // 64-lane butterfly reduction; lane 0 stores the wave's 16xTN tile.
#pragma unroll
    for (int i = 0; i < BDIM; ++i)
#pragma unroll
        for (int j = 0; j < TN; ++j) {
            float v = acc[i][j];
#pragma unroll
            for (int off = 32; off >= 1; off >>= 1) v += __shfl_xor(v, off, 64);
            acc[i][j] = v;
        }

    if (lane == 0) {
#pragma unroll
        for (int j = 0; j < TN; ++j) {
            const float b = bias[n0 + j];
#pragma unroll
            for (int i = 0; i < BDIM; ++i)
                out[(size_t)i * NDIM + (n0 + j)] = acc[i][j] + b;
        }
    }
}

extern "C" void kernel_launch(void* const* d_in, const int* in_sizes, int n_in,
                              void* d_out, int out_size, void* d_ws, size_t ws_size,
                              hipStream_t stream) {
    const float* x      = (const float*)d_in[0];
    const int*   qw     = (const int*)d_in[1];
    const float* scales = (const float*)d_in[2];
    const float* bias   = (const float*)d_in[3];
    float*       out    = (float*)d_out;

    dim3 grid(NDIM / ROWS_PER_BLOCK);   // 512 blocks = 2 per CU
    dim3 block(256);                     // 4 waves
    int8lin_kernel<<<grid, block, 0, stream>>>(x, qw, scales, bias, out);
}